// Round 4
// baseline (910.868 us; speedup 1.0000x reference)
//
#include <hip/hip_runtime.h>
#include <stdint.h>

#define HIDD 128
#define NNODES 100000
#define NEDGES 800000

typedef short s16x8 __attribute__((ext_vector_type(8)));
typedef float f32x4 __attribute__((ext_vector_type(4)));

__device__ __forceinline__ short f2bf(float f) {
  union { float f; unsigned u; } v; v.f = f;
  return (short)((v.u + 0x7fffu + ((v.u >> 16) & 1u)) >> 16);
}
__device__ __forceinline__ short4 cvt4(float4 v) {
  short4 s; s.x = f2bf(v.x); s.y = f2bf(v.y); s.z = f2bf(v.z); s.w = f2bf(v.w);
  return s;
}
__device__ __forceinline__ float bflo(unsigned w) {
  union { unsigned u; float f; } v; v.u = w << 16; return v.f;
}
__device__ __forceinline__ float bfhi(unsigned w) {
  union { unsigned u; float f; } v; v.u = w & 0xffff0000u; return v.f;
}
__device__ __forceinline__ unsigned pack2(float a, float b) {
  return ((unsigned)(unsigned short)f2bf(b) << 16) | (unsigned)(unsigned short)f2bf(a);
}
__device__ __forceinline__ f32x4 mfma16(s16x8 a, s16x8 b, f32x4 c) {
  return __builtin_amdgcn_mfma_f32_16x16x32_bf16(a, b, c, 0, 0, 0);
}
__device__ __forceinline__ void atomic_pk_bf16(unsigned short* addr, unsigned pk) {
  asm volatile("global_atomic_pk_add_bf16 %0, %1, off" :: "v"(addr), "v"(pk) : "memory");
}

// ---------- prep: h -> bf16 ----------
__global__ void k_prep_h(const float4* __restrict__ h4, short4* __restrict__ hb4, int n4) {
  int stride = gridDim.x * blockDim.x;
  for (int i = blockIdx.x * blockDim.x + threadIdx.x; i < n4; i += stride)
    hb4[i] = cvt4(h4[i]);
}

// ---------- prep: weights -> bf16 [out][in]; w2e additionally col-permuted ----------
__global__ void k_prep_w(const float* __restrict__ w1e, const float* __restrict__ w2e,
                         const float* __restrict__ w1u, const float* __restrict__ w2u,
                         short* __restrict__ w1et, short* __restrict__ w2et,
                         short* __restrict__ w1ut, short* __restrict__ w2ut) {
  int i = blockIdx.x * 256 + threadIdx.x;
  if (i < 49152) {               // dest [128][384]: n=i/384, k=i%384
    int n = i / 384, k = i - n * 384;
    w1et[i] = f2bf(w1e[k * 128 + n]);
    w1ut[i] = f2bf(w1u[k * 128 + n]);
  } else {
    int j = i - 49152;
    if (j < 16384) {             // dest [128][128]: n=j>>7, k=j&127
      int n = j >> 7, k = j & 127;
      int oc = (n & ~31) + 2 * (n & 15) + ((n >> 4) & 1);
      w2et[j] = f2bf(w2e[k * 128 + oc]);   // permuted for pk-atomic epilogue
      w2ut[j] = f2bf(w2u[k * 128 + n]);    // natural
    }
  }
}

// ---------- edge: direct per-lane h gather, small LDS, 3 blocks/CU ----------
__global__ __launch_bounds__(256, 3)
void k_edge(const short* __restrict__ hb, const int* __restrict__ eidx,
            const float* __restrict__ ex,
            const short* __restrict__ w1t, const short* __restrict__ w2t,
            const float* __restrict__ b1g, const float* __restrict__ b2g,
            unsigned short* __restrict__ incb, unsigned short* __restrict__ outgb,
            float* __restrict__ indeg, float* __restrict__ outdeg) {
  __shared__ __align__(16) short Xe[64][140];   // edge_x bf16, 17920 B
  __shared__ __align__(16) short Hs[64][140];   // hidden  bf16, 17920 B

  const int tid = threadIdx.x;
  const int wave = tid >> 6, lane = tid & 63;
  const int lg = lane >> 4, lr = lane & 15;
  const int koff = lg * 8;
  const int c0 = wave * 32 + lr, c1 = c0 + 16;   // layer-1 (natural) cols
  const int pc0 = wave * 32 + 2 * lr;            // layer-2 physical col (even)

  // W1 fragments resident: 24 x s16x8 = 96 VGPRs
  s16x8 wb1a[12], wb1b[12];
#pragma unroll
  for (int kk = 0; kk < 12; ++kk) {
    wb1a[kk] = *(const s16x8*)(w1t + c0 * 384 + kk * 32 + koff);
    wb1b[kk] = *(const s16x8*)(w1t + c1 * 384 + kk * 32 + koff);
  }
  const float bias1_0 = b1g[c0], bias1_1 = b1g[c1];
  const float bias2_0 = b2g[pc0], bias2_1 = b2g[pc0 + 1];

  for (int t = blockIdx.x; t < NEDGES / 64; t += gridDim.x) {
    const int base = t * 64;

    // stage edge_x (f32 -> bf16) into Xe; other LDS untouched by in-flight phases
    for (int u = tid; u < 64 * 16; u += 256) {
      int r = u >> 4, c = u & 15;
      const float* p = ex + (long)(base + r) * 128 + c * 8;
      float4 v0 = *(const float4*)p;
      float4 v1 = *(const float4*)(p + 4);
      short4 s0 = cvt4(v0), s1 = cvt4(v1);
      *(int4*)&Xe[r][c * 8] = make_int4(
        (int)(unsigned short)s0.x | ((int)(unsigned short)s0.y << 16),
        (int)(unsigned short)s0.z | ((int)(unsigned short)s0.w << 16),
        (int)(unsigned short)s1.x | ((int)(unsigned short)s1.y << 16),
        (int)(unsigned short)s1.z | ((int)(unsigned short)s1.w << 16));
    }
    if (tid < 64) {
      atomicAdd(&outdeg[eidx[base + tid]], 1.0f);
      atomicAdd(&indeg[eidx[NEDGES + base + tid]], 1.0f);
    }
    // per-lane gather rows (row = m*16 + lr)
    int sn[4], dn[4];
#pragma unroll
    for (int m = 0; m < 4; ++m) {
      sn[m] = eidx[base + m * 16 + lr];
      dn[m] = eidx[NEDGES + base + m * 16 + lr];
    }
    __syncthreads();   // Xe ready (also: all waves' prior-tile L2 reads retired)

    // Layer 1: A-fragments gathered directly from hb (src, dst) + Xe (edge_x)
    f32x4 acc[4][2] = {};
#pragma unroll
    for (int m = 0; m < 4; ++m) {
      const short* ps = hb + (long)sn[m] * 128 + koff;
      {
        s16x8 a0 = *(const s16x8*)(ps);
        s16x8 a1 = *(const s16x8*)(ps + 32);
        s16x8 a2 = *(const s16x8*)(ps + 64);
        s16x8 a3 = *(const s16x8*)(ps + 96);
        acc[m][0] = mfma16(a0, wb1a[0], acc[m][0]); acc[m][1] = mfma16(a0, wb1b[0], acc[m][1]);
        acc[m][0] = mfma16(a1, wb1a[1], acc[m][0]); acc[m][1] = mfma16(a1, wb1b[1], acc[m][1]);
        acc[m][0] = mfma16(a2, wb1a[2], acc[m][0]); acc[m][1] = mfma16(a2, wb1b[2], acc[m][1]);
        acc[m][0] = mfma16(a3, wb1a[3], acc[m][0]); acc[m][1] = mfma16(a3, wb1b[3], acc[m][1]);
      }
      const short* pd = hb + (long)dn[m] * 128 + koff;
      {
        s16x8 a0 = *(const s16x8*)(pd);
        s16x8 a1 = *(const s16x8*)(pd + 32);
        s16x8 a2 = *(const s16x8*)(pd + 64);
        s16x8 a3 = *(const s16x8*)(pd + 96);
        acc[m][0] = mfma16(a0, wb1a[4], acc[m][0]); acc[m][1] = mfma16(a0, wb1b[4], acc[m][1]);
        acc[m][0] = mfma16(a1, wb1a[5], acc[m][0]); acc[m][1] = mfma16(a1, wb1b[5], acc[m][1]);
        acc[m][0] = mfma16(a2, wb1a[6], acc[m][0]); acc[m][1] = mfma16(a2, wb1b[6], acc[m][1]);
        acc[m][0] = mfma16(a3, wb1a[7], acc[m][0]); acc[m][1] = mfma16(a3, wb1b[7], acc[m][1]);
      }
#pragma unroll
      for (int kk = 0; kk < 4; ++kk) {
        s16x8 a = *(const s16x8*)&Xe[m * 16 + lr][kk * 32 + koff];
        acc[m][0] = mfma16(a, wb1a[8 + kk], acc[m][0]);
        acc[m][1] = mfma16(a, wb1b[8 + kk], acc[m][1]);
      }
    }
#pragma unroll
    for (int m = 0; m < 4; ++m)
#pragma unroll
      for (int r2 = 0; r2 < 4; ++r2) {
        int row = m * 16 + lg * 4 + r2;
        Hs[row][c0] = f2bf(fmaxf(acc[m][0][r2] + bias1_0, 0.f));
        Hs[row][c1] = f2bf(fmaxf(acc[m][1][r2] + bias1_1, 0.f));
      }
    __syncthreads();   // Hs ready

    // Layer 2: W2 fragments reloaded from L2-hot w2t (saves VGPRs)
    f32x4 acc2[4][2] = {};
#pragma unroll
    for (int kk = 0; kk < 4; ++kk) {
      s16x8 w2a = *(const s16x8*)(w2t + c0 * 128 + kk * 32 + koff);
      s16x8 w2b = *(const s16x8*)(w2t + c1 * 128 + kk * 32 + koff);
#pragma unroll
      for (int m = 0; m < 4; ++m) {
        s16x8 a = *(const s16x8*)&Hs[m * 16 + lr][kk * 32 + koff];
        acc2[m][0] = mfma16(a, w2a, acc2[m][0]);
        acc2[m][1] = mfma16(a, w2b, acc2[m][1]);
      }
    }
#pragma unroll
    for (int m = 0; m < 4; ++m)
#pragma unroll
      for (int r2 = 0; r2 < 4; ++r2) {
        int row = m * 16 + lg * 4 + r2;
        int s = eidx[base + row], d = eidx[NEDGES + base + row];
        unsigned pk = pack2(acc2[m][0][r2] + bias2_0, acc2[m][1][r2] + bias2_1);
        atomic_pk_bf16(outgb + (long)s * 128 + pc0, pk);
        atomic_pk_bf16(incb + (long)d * 128 + pc0, pk);
      }
    // next iteration's Xe staging is safe: all waves passed the Hs barrier,
    // so every wave's layer-1 Xe reads have retired.
  }
}

// ---------- node: X=[hb | inc/deg | outg/deg] -> MLP -> residual+LN ----------
__global__ __launch_bounds__(256, 2)
void k_node(const float* __restrict__ h, const short* __restrict__ hb,
            const unsigned short* __restrict__ incb,
            const unsigned short* __restrict__ outgb,
            const float* __restrict__ indeg, const float* __restrict__ outdeg,
            const short* __restrict__ w1t, const short* __restrict__ w2t,
            const float* __restrict__ b1g, const float* __restrict__ b2g,
            const float* __restrict__ lng, const float* __restrict__ lnb,
            float* __restrict__ out) {
  __shared__ __align__(16) char smem[67584];
  short (*Xs)[392] = (short (*)[392])smem;            // 50176 B
  float (*Xf)[132] = (float (*)[132])smem;            // 33792 B, overlays Xs
  short (*Hs)[136] = (short (*)[136])(smem + 50176);  // 17408 B

  const int tid = threadIdx.x;
  const int wave = tid >> 6, lane = tid & 63;
  const int lg = lane >> 4, lr = lane & 15;
  const int koff = lg * 8;
  const int c0 = wave * 32 + lr, c1 = c0 + 16;

  s16x8 wb1a[12], wb1b[12], wb2a[4], wb2b[4];
#pragma unroll
  for (int kk = 0; kk < 12; ++kk) {
    wb1a[kk] = *(const s16x8*)(w1t + c0 * 384 + kk * 32 + koff);
    wb1b[kk] = *(const s16x8*)(w1t + c1 * 384 + kk * 32 + koff);
  }
#pragma unroll
  for (int kk = 0; kk < 4; ++kk) {
    wb2a[kk] = *(const s16x8*)(w2t + c0 * 128 + kk * 32 + koff);
    wb2b[kk] = *(const s16x8*)(w2t + c1 * 128 + kk * 32 + koff);
  }
  const float bias1_0 = b1g[c0], bias1_1 = b1g[c1];
  const float bias2_0 = b2g[c0], bias2_1 = b2g[c1];

  const int ntiles = (NNODES + 63) / 64;
  for (int t = blockIdx.x; t < ntiles; t += gridDim.x) {
    const int base = t * 64;

    for (int u = tid; u < 64 * 16; u += 256) {     // hb straight copy
      int r = u >> 4, c = u & 15;
      long node = min(base + r, NNODES - 1);
      *(int4*)&Xs[r][c * 8] = *(const int4*)(hb + node * 128 + c * 8);
    }
    for (int u = tid; u < 64 * 16; u += 256) {     // incb scaled
      int r = u >> 4, c = u & 15;
      long node = min(base + r, NNODES - 1);
      float s = 1.f / fmaxf(indeg[node], 1.f);
      uint4 w = *(const uint4*)(incb + node * 128 + c * 8);
      unsigned o0 = pack2(bflo(w.x) * s, bfhi(w.x) * s);
      unsigned o1 = pack2(bflo(w.y) * s, bfhi(w.y) * s);
      unsigned o2 = pack2(bflo(w.z) * s, bfhi(w.z) * s);
      unsigned o3 = pack2(bflo(w.w) * s, bfhi(w.w) * s);
      *(uint4*)&Xs[r][128 + c * 8] = make_uint4(o0, o1, o2, o3);
    }
    for (int u = tid; u < 64 * 16; u += 256) {     // outgb scaled
      int r = u >> 4, c = u & 15;
      long node = min(base + r, NNODES - 1);
      float s = 1.f / fmaxf(outdeg[node], 1.f);
      uint4 w = *(const uint4*)(outgb + node * 128 + c * 8);
      unsigned o0 = pack2(bflo(w.x) * s, bfhi(w.x) * s);
      unsigned o1 = pack2(bflo(w.y) * s, bfhi(w.y) * s);
      unsigned o2 = pack2(bflo(w.z) * s, bfhi(w.z) * s);
      unsigned o3 = pack2(bflo(w.w) * s, bfhi(w.w) * s);
      *(uint4*)&Xs[r][256 + c * 8] = make_uint4(o0, o1, o2, o3);
    }
    __syncthreads();

    f32x4 acc[4][2] = {};
#pragma unroll
    for (int kk = 0; kk < 12; ++kk) {
      int k0 = kk * 32 + koff;
#pragma unroll
      for (int m = 0; m < 4; ++m) {
        s16x8 a = *(const s16x8*)&Xs[m * 16 + lr][k0];
        acc[m][0] = mfma16(a, wb1a[kk], acc[m][0]);
        acc[m][1] = mfma16(a, wb1b[kk], acc[m][1]);
      }
    }
#pragma unroll
    for (int m = 0; m < 4; ++m)
#pragma unroll
      for (int r2 = 0; r2 < 4; ++r2) {
        int row = m * 16 + lg * 4 + r2;
        Hs[row][c0] = f2bf(fmaxf(acc[m][0][r2] + bias1_0, 0.f));
        Hs[row][c1] = f2bf(fmaxf(acc[m][1][r2] + bias1_1, 0.f));
      }
    __syncthreads();

    f32x4 acc2[4][2] = {};
#pragma unroll
    for (int kk = 0; kk < 4; ++kk) {
      int k0 = kk * 32 + koff;
#pragma unroll
      for (int m = 0; m < 4; ++m) {
        s16x8 a = *(const s16x8*)&Hs[m * 16 + lr][k0];
        acc2[m][0] = mfma16(a, wb2a[kk], acc2[m][0]);
        acc2[m][1] = mfma16(a, wb2b[kk], acc2[m][1]);
      }
    }
#pragma unroll
    for (int m = 0; m < 4; ++m)
#pragma unroll
      for (int r2 = 0; r2 < 4; ++r2) {
        int row = m * 16 + lg * 4 + r2;
        long node = base + row;
        float h0 = 0.f, h1 = 0.f;
        if (node < NNODES) { h0 = h[node * 128 + c0]; h1 = h[node * 128 + c1]; }
        Xf[row][c0] = acc2[m][0][r2] + bias2_0 + h0;
        Xf[row][c1] = acc2[m][1][r2] + bias2_1 + h1;
      }
    __syncthreads();

    {
      int r = tid >> 2, q = tid & 3;
      float sum = 0.f, ss = 0.f;
      float4 vals[8];
#pragma unroll
      for (int j = 0; j < 8; ++j) {
        float4 v = *(const float4*)&Xf[r][q * 32 + j * 4];
        vals[j] = v;
        sum += v.x + v.y + v.z + v.w;
        ss += v.x * v.x + v.y * v.y + v.z * v.z + v.w * v.w;
      }
      sum += __shfl_xor(sum, 1); sum += __shfl_xor(sum, 2);
      ss  += __shfl_xor(ss, 1);  ss  += __shfl_xor(ss, 2);
      float mean = sum * (1.f / 128.f);
      float var = ss * (1.f / 128.f) - mean * mean;
      float rstd = rsqrtf(var + 1e-5f);
      long node = base + r;
      if (node < NNODES) {
#pragma unroll
        for (int j = 0; j < 8; ++j) {
          int cc = q * 32 + j * 4;
          float4 v = vals[j];
          float4 o;
          o.x = (v.x - mean) * rstd * lng[cc + 0] + lnb[cc + 0];
          o.y = (v.y - mean) * rstd * lng[cc + 1] + lnb[cc + 1];
          o.z = (v.z - mean) * rstd * lng[cc + 2] + lnb[cc + 2];
          o.w = (v.w - mean) * rstd * lng[cc + 3] + lnb[cc + 3];
          *(float4*)(out + node * 128 + cc) = o;
        }
      }
    }
    __syncthreads();
  }
}

extern "C" void kernel_launch(void* const* d_in, const int* in_sizes, int n_in,
                              void* d_out, int out_size, void* d_ws, size_t ws_size,
                              hipStream_t stream) {
  const float* h    = (const float*)d_in[0];
  const int*   ei   = (const int*)d_in[1];
  const float* ex   = (const float*)d_in[2];
  const float* epw1 = (const float*)d_in[3];
  const float* epb1 = (const float*)d_in[4];
  const float* epw2 = (const float*)d_in[5];
  const float* epb2 = (const float*)d_in[6];
  const float* upw1 = (const float*)d_in[7];
  const float* upb1 = (const float*)d_in[8];
  const float* upw2 = (const float*)d_in[9];
  const float* upb2 = (const float*)d_in[10];
  const float* lng  = (const float*)d_in[11];
  const float* lnb  = (const float*)d_in[12];
  float* out = (float*)d_out;

  char* ws = (char*)d_ws;
  unsigned short* incb  = (unsigned short*)(ws);             // 25,600,000 B
  unsigned short* outgb = (unsigned short*)(ws + 25600000);  // 25,600,000 B
  float* indeg  = (float*)(ws + 51200000);                   //    400,000 B
  float* outdeg = (float*)(ws + 51600000);                   //    400,000 B
  short* hb     = (short*)(ws + 52000000);                   // 25,600,000 B
  short* w1et   = (short*)(ws + 77600000);                   //     98,304 B
  short* w2et   = (short*)(ws + 77698304);                   //     32,768 B
  short* w1ut   = (short*)(ws + 77731072);                   //     98,304 B
  short* w2ut   = (short*)(ws + 77829376);                   //     32,768 B

  hipMemsetAsync(ws, 0, 52000000, stream);   // incb+outgb+degrees
  hipLaunchKernelGGL(k_prep_h, dim3(2048), dim3(256), 0, stream,
                     (const float4*)h, (short4*)hb, NNODES * 128 / 4);
  hipLaunchKernelGGL(k_prep_w, dim3(256), dim3(256), 0, stream,
                     epw1, epw2, upw1, upw2, w1et, w2et, w1ut, w2ut);
  hipLaunchKernelGGL(k_edge, dim3(2048), dim3(256), 0, stream,
                     hb, ei, ex, w1et, w2et, epb1, epb2, incb, outgb, indeg, outdeg);
  hipLaunchKernelGGL(k_node, dim3(512), dim3(256), 0, stream,
                     h, hb, incb, outgb, indeg, outdeg, w1ut, w2ut, upb1, upb2,
                     lng, lnb, out);
}